// Round 1
// baseline (175.360 us; speedup 1.0000x reference)
//
#include <hip/hip_runtime.h>
#include <math.h>

#define LVL 16
#define TBL 65536
#define BATCH 8
#define NPIX 65536       // 256*256
#define SDIM 512
#define HPRIME 2654435761u

typedef __attribute__((ext_vector_type(2))) float f32x2;

struct ResPack { int r[LVL]; };
struct OffPack { int o[LVL]; };   // prefix offsets into the blended-row LDS array

// ws layout (floats): [0, 17152) weff (8 batches x 2144), paired layout.
#define WEFF_STRIDE 2144

// ---------------------------------------------------------------------------
// Kernel A: fused style + demod + weff emit.
// Grid 24 blocks: b = blk&7 (XCD affinity), l = blk>>3 (layer 0/1/2).
// Each block computes its layer's 32 style dots (s[b] . aw_l rows), demod,
// and emits its weff slice in the PAIRED layout the fused kernel consumes.
// No cross-layer dependency -> no redundancy, no separate style kernel.
// ---------------------------------------------------------------------------
__global__ __launch_bounds__(256) void weff_kernel(
    const float* __restrict__ s,
    const float* __restrict__ aw0, const float* __restrict__ ab0,
    const float* __restrict__ aw1, const float* __restrict__ ab1,
    const float* __restrict__ aw2, const float* __restrict__ ab2,
    const float* __restrict__ w0, const float* __restrict__ w1,
    const float* __restrict__ w2,
    float* __restrict__ ws)
{
    const int b = blockIdx.x & 7;
    const int l = blockIdx.x >> 3;
    const int tid = (int)threadIdx.x;
    const int wave = tid >> 6, lane = tid & 63;

    const float* aw; const float* ab; const float* w; int nout;
    if (l == 0)      { aw = aw0; ab = ab0; w = w0; nout = 32; }
    else if (l == 1) { aw = aw1; ab = ab1; w = w1; nout = 32; }
    else             { aw = aw2; ab = ab2; w = w2; nout = 3;  }

    __shared__ float st[32];
    __shared__ float dem[32];

    // ---- style: 32 rows x dot(512). 4 waves x 8 rows, 2 chains per iter.
    const float* sb = s + b * SDIM;
    for (int r0 = wave * 8; r0 < wave * 8 + 8; r0 += 2) {
        const float* rowA = aw + (size_t)r0 * SDIM;
        const float* rowB = aw + (size_t)(r0 + 1) * SDIM;
        float a0 = 0.f, a1 = 0.f;
        #pragma unroll
        for (int j = 0; j < SDIM / 64; ++j) {
            const int k = lane + j * 64;
            const float sv = sb[k];
            a0 += sv * rowA[k];
            a1 += sv * rowB[k];
        }
        #pragma unroll
        for (int off = 32; off >= 1; off >>= 1) {
            a0 += __shfl_xor(a0, off, 64);
            a1 += __shfl_xor(a1, off, 64);
        }
        if (lane == 0) { st[r0] = a0 + ab[r0]; st[r0 + 1] = a1 + ab[r0 + 1]; }
    }
    __syncthreads();

    // ---- demod: o = tid>>3 (0..31), 8 lanes each sum 4 squares + butterfly.
    {
        const int o = tid >> 3, sub = tid & 7;
        if (o < nout) {
            float sum = 0.f;
            #pragma unroll
            for (int j = 0; j < 4; ++j) {
                const int i = sub * 4 + j;
                const float v = w[o * 32 + i] * st[i];
                sum += v * v;
            }
            sum += __shfl_xor(sum, 4, 64);
            sum += __shfl_xor(sum, 2, 64);
            sum += __shfl_xor(sum, 1, 64);
            if (sub == 0) dem[o] = 1.0f / sqrtf(sum + 1e-8f);
        }
    }
    __syncthreads();

    // ---- emit paired layout (same formulas/order as the verified kernel).
    float* outp = ws + (size_t)b * WEFF_STRIDE;
    if (l < 2) {
        const int base = l * 1024;
        for (int idx = tid; idx < 1024; idx += 256) {
            const int o2 = idx >> 6, rem = idx & 63, i = rem >> 1, h = rem & 1;
            const int oo = o2 + 16 * h;
            outp[base + idx] = w[oo * 32 + i] * st[i] * dem[oo];
        }
    } else {
        if (tid < 96) {
            const int oo = tid >> 5, i = tid & 31;
            outp[2048 + tid] = w[tid] * st[i] * dem[oo];
        }
    }
}

// ---------------------------------------------------------------------------
// Kernel B: fused hash-grid + MLP. One block = one (batch, image-row).
// Row-uniform y => per level only 2 table rows are touched and fy is uniform,
// so a cooperative fill stage pre-blends them into LDS: 2*sum(R_l) ~= 2900
// scattered gathers per BLOCK (was 16384), then the per-pixel phase is pure
// LDS reads + VALU. MLP is the verified paired-packed fp32 path, unchanged.
// ---------------------------------------------------------------------------
__global__ __launch_bounds__(256) void fused_kernel(
    const float* __restrict__ tables,   // [B, L, T, 2]
    const float* __restrict__ coords,   // [N, 2]
    const float* __restrict__ weff,     // ws: paired weights per batch
    const float* __restrict__ b0, const float* __restrict__ b1, const float* __restrict__ b2,
    float* __restrict__ out,            // [B, 3, 256, 256]
    ResPack rp, OffPack op)
{
    const int b     = blockIdx.x & 7;           // XCD-affinity: batch <-> XCD
    const int chunk = blockIdx.x >> 3;          // image row
    const int tid   = (int)threadIdx.x;
    const int n     = chunk * 256 + tid;

    __shared__ float2 blend[1600];              // sum(R_l) ~= 1450 float2

    const float* tb = tables + (size_t)b * (LVL * TBL * 2);

    // Row-uniform cy (all pixels of this block share coords[...,1]).
    const float cy = coords[(chunk << 9) + 1];

    // ---- fill: per level, thread tid handles grid column x = tid (< R).
    #pragma unroll
    for (int l = 0; l < LVL; ++l) {
        const int R = rp.r[l];
        if (tid < R) {
            const float rm1 = (float)(R - 1);
            const float py  = cy * rm1;
            const float fpy = floorf(py);
            const float fy  = py - fpy;
            int y0 = (int)fpy;
            int y1 = y0 + 1; if (y1 > R - 1) y1 = R - 1;
            const unsigned hy0 = (unsigned)y0 * HPRIME;
            const unsigned hy1 = (unsigned)y1 * HPRIME;
            const unsigned x   = (unsigned)tid;
            const unsigned h0  = (x ^ hy0) & 0xFFFFu;
            const unsigned h1  = (x ^ hy1) & 0xFFFFu;
            const float2* tl = (const float2*)tb + (size_t)l * TBL;
            const float2 g0 = tl[h0];
            const float2 g1 = tl[h1];
            float2 r;
            r.x = g0.x * (1.f - fy) + g1.x * fy;
            r.y = g0.y * (1.f - fy) + g1.y * fy;
            blend[op.o[l] + tid] = r;
        }
    }
    __syncthreads();

    // ---- per-pixel: x-interp from pre-blended LDS rows.
    const float cx = coords[2 * n];
    float feat[32];
    #pragma unroll
    for (int l = 0; l < LVL; ++l) {
        const int R = rp.r[l];
        const float rm1 = (float)(R - 1);
        const float px  = cx * rm1;
        const float fpx = floorf(px);
        const float fx  = px - fpx;
        int x0 = (int)fpx;
        int x1 = x0 + 1; if (x1 > R - 1) x1 = R - 1;
        const int base = op.o[l];
        const float2 gA = blend[base + x0];
        const float2 gB = blend[base + x1];
        feat[2 * l]     = gA.x * (1.f - fx) + gB.x * fx;
        feat[2 * l + 1] = gA.y * (1.f - fx) + gB.y * fx;
    }

    const f32x2* W0p = (const f32x2*)(weff + (size_t)b * WEFF_STRIDE);         // [16][32]
    const f32x2* W1p = W0p + 512;                                              // [16][32]
    const float* W2  = weff + (size_t)b * WEFF_STRIDE + 2048;                  // [3][32]

    // layer 0: paired outputs {o2, o2+16}
    f32x2 h1p[16];
    #pragma unroll
    for (int o2 = 0; o2 < 16; ++o2) {
        f32x2 acc; acc[0] = b0[o2]; acc[1] = b0[o2 + 16];
        #pragma unroll
        for (int i = 0; i < 32; ++i) {
            f32x2 fb; fb[0] = feat[i]; fb[1] = feat[i];
            acc += W0p[o2 * 32 + i] * fb;
        }
        acc[0] = fmaxf(acc[0], 0.f); acc[1] = fmaxf(acc[1], 0.f);
        h1p[o2] = acc;
    }

    // layer 1
    f32x2 h2p[16];
    #pragma unroll
    for (int o2 = 0; o2 < 16; ++o2) {
        f32x2 acc; acc[0] = b1[o2]; acc[1] = b1[o2 + 16];
        #pragma unroll
        for (int i = 0; i < 32; ++i) {
            const float hv = h1p[i & 15][i >> 4];
            f32x2 fb; fb[0] = hv; fb[1] = hv;
            acc += W1p[o2 * 32 + i] * fb;
        }
        acc[0] = fmaxf(acc[0], 0.f); acc[1] = fmaxf(acc[1], 0.f);
        h2p[o2] = acc;
    }

    // layer 2 (3 outputs, scalar)
    #pragma unroll
    for (int o = 0; o < 3; ++o) {
        float acc = b2[o];
        #pragma unroll
        for (int i = 0; i < 32; ++i)
            acc = fmaf(W2[o * 32 + i], h2p[i & 15][i >> 4], acc);
        out[((size_t)(b * 3 + o) << 16) + n] = tanhf(acc);
    }
}

// ---------------------------------------------------------------------------
extern "C" void kernel_launch(void* const* d_in, const int* in_sizes, int n_in,
                              void* d_out, int out_size, void* d_ws, size_t ws_size,
                              hipStream_t stream) {
    const float* x      = (const float*)d_in[0];
    const float* s      = (const float*)d_in[1];
    const float* coords = (const float*)d_in[2];
    const float* w0  = (const float*)d_in[3];
    const float* aw0 = (const float*)d_in[4];
    const float* ab0 = (const float*)d_in[5];
    const float* b0  = (const float*)d_in[6];
    const float* w1  = (const float*)d_in[7];
    const float* aw1 = (const float*)d_in[8];
    const float* ab1 = (const float*)d_in[9];
    const float* b1  = (const float*)d_in[10];
    const float* w2  = (const float*)d_in[11];
    const float* aw2 = (const float*)d_in[12];
    const float* ab2 = (const float*)d_in[13];
    const float* b2  = (const float*)d_in[14];
    float* out = (float*)d_out;
    float* ws  = (float*)d_ws;    // 17152 floats = 68608 B

    ResPack rp; OffPack op;
    const double g = pow(256.0 / 16.0, 1.0 / 15.0);
    int cum = 0;
    for (int l = 0; l < LVL; ++l) {
        double r = 16.0 * pow(g, (double)l);
        long ri = lround(r);
        if (ri > 256) ri = 256;
        rp.r[l] = (int)ri;
        op.o[l] = cum;
        cum += (int)ri;
    }

    hipLaunchKernelGGL(weff_kernel, dim3(24), dim3(256), 0, stream,
                       s, aw0, ab0, aw1, ab1, aw2, ab2, w0, w1, w2, ws);
    hipLaunchKernelGGL(fused_kernel, dim3(NPIX / 256 * BATCH), dim3(256), 0, stream,
                       x, coords, ws, b0, b1, b2, out, rp, op);
}